// Round 3
// baseline (15616.611 us; speedup 1.0000x reference)
//
#include <hip/hip_runtime.h>
#include <stdint.h>

#define T_LEN 4096
#define NVOC 256
#define EMBD 512
#define HID 512
#define G4 2048
#define NEGV (-10000.0f)
#define START_TAG 0
#define STOP_TAG 1
#define NPROD 32   // workgroups per LSTM direction

// raw workgroup barrier: wait LDS ops only (no vmcnt drain)
#define BAR_LGKM() do { \
    asm volatile("s_waitcnt lgkmcnt(0)\n\ts_barrier" ::: "memory"); \
    __builtin_amdgcn_sched_barrier(0); \
} while (0)

// ---------------- generic C[M,N] = A[M,K] @ B[N,K]^T + bias0 + bias1 ----------------
__global__ __launch_bounds__(256) void gemm_abt(
    const float* __restrict__ A, const float* __restrict__ B,
    const float* __restrict__ bias0, const float* __restrict__ bias1,
    float* __restrict__ C, int M, int N, int K)
{
    __shared__ float As[16][65];
    __shared__ float Bs[16][65];
    int m0 = blockIdx.x * 64, n0 = blockIdx.y * 64;
    int tid = threadIdx.x;
    int lr = tid >> 2;          // 0..63
    int lk = (tid & 3) << 2;    // 0,4,8,12
    int tr = tid & 15, tc = tid >> 4;
    float acc[4][4] = {};
    for (int k0 = 0; k0 < K; k0 += 16) {
        float4 av = *(const float4*)(A + (size_t)(m0 + lr) * K + k0 + lk);
        float4 bv = *(const float4*)(B + (size_t)(n0 + lr) * K + k0 + lk);
        As[lk + 0][lr] = av.x; As[lk + 1][lr] = av.y; As[lk + 2][lr] = av.z; As[lk + 3][lr] = av.w;
        Bs[lk + 0][lr] = bv.x; Bs[lk + 1][lr] = bv.y; Bs[lk + 2][lr] = bv.z; Bs[lk + 3][lr] = bv.w;
        __syncthreads();
#pragma unroll
        for (int kk = 0; kk < 16; ++kk) {
            float a[4], b[4];
#pragma unroll
            for (int x = 0; x < 4; ++x) a[x] = As[kk][tr * 4 + x];
#pragma unroll
            for (int y = 0; y < 4; ++y) b[y] = Bs[kk][tc * 4 + y];
#pragma unroll
            for (int y = 0; y < 4; ++y)
#pragma unroll
                for (int x = 0; x < 4; ++x)
                    acc[y][x] += a[x] * b[y];
        }
        __syncthreads();
    }
#pragma unroll
    for (int y = 0; y < 4; ++y) {
        int n = n0 + tc * 4 + y;
        float bb = bias0 ? bias0[n] : 0.f;
        if (bias1) bb += bias1[n];
#pragma unroll
        for (int x = 0; x < 4; ++x)
            C[(size_t)(m0 + tr * 4 + x) * N + n] = acc[y][x] + bb;
    }
}

__device__ __forceinline__ float fast_sig(float x) {
    return __builtin_amdgcn_rcpf(1.f + __expf(-x));
}
__device__ __forceinline__ float fast_tanh(float x) {
    return 2.f * __builtin_amdgcn_rcpf(1.f + __expf(-2.f * x)) - 1.f;
}

// ---------------- persistent BiLSTM, fence-free exchange, ONE barrier/step ----------------
// 64 blocks x 256 threads. blocks 0..31: forward, 32..63: backward.
// thread map: u = tid>>4 (unit), g = (tid>>2)&3 (gate), q = tid&3 (col quarter)
// -> all 4 gates of a unit in one 16-lane cluster: gate gather via shfl, no LDS.
// h_sh double-buffered by step parity -> single lgkmcnt-only barrier per step.
__global__ __launch_bounds__(256) void lstm_kernel(
    const int* __restrict__ src,
    const float* __restrict__ PE_f, const float* __restrict__ PE_b,
    const float* __restrict__ Whh_f, const float* __restrict__ Whh_b,
    float* __restrict__ H, unsigned long long* __restrict__ pub)
{
    int wg  = blockIdx.x & 31;
    int dir = blockIdx.x >> 5;          // 0 = fwd, 1 = bwd
    const float* PE  = dir ? PE_b : PE_f;
    const float* Whh = dir ? Whh_b : Whh_f;
    unsigned long long* mypub = pub + (size_t)dir * 1024;   // [slot][512]

    int tid = threadIdx.x;
    int u = tid >> 4;                   // unit 0..15
    int g = (tid >> 2) & 3;             // gate 0..3 (i,f,g,o)
    int q = tid & 3;                    // column quarter
    int hu0 = wg * 16;
    int grow = g * 512 + hu0 + u;       // global gate row

    // weights -> registers (32 float4 = 128 VGPR)
    float4 w4[32];
    const float4* wsrc = (const float4*)(Whh + (size_t)grow * 512 + q * 128);
#pragma unroll
    for (int j = 0; j < 32; ++j) w4[j] = wsrc[j];

    // double-buffered, padded: quarter stride 132 floats
    __shared__ __align__(16) float h_sh[2][4][132];
    float c_state = 0.f;                // valid in leader lanes
    bool leader = ((tid & 15) == 0);

    int e0 = tid * 2;                   // this thread delivers elements e0, e0+1
    int pq = e0 >> 7, pj = e0 & 127;

    for (int s = 0; s < T_LEN; ++s) {
        int par = s & 1;
        int t = dir ? (T_LEN - 1 - s) : s;
        int st = src[t];
        float pe0 = 0.f, pe1 = 0.f, pe2 = 0.f, pe3 = 0.f;
        if (leader) {                    // prefetch input-projection early
            const float* pb = PE + (size_t)st * G4 + hu0 + u;
            pe0 = pb[0]; pe1 = pb[512]; pe2 = pb[1024]; pe3 = pb[1536];
        }
        if (s == 0) {
            h_sh[0][pq][pj] = 0.f; h_sh[0][pq][pj + 1] = 0.f;
        } else {
            unsigned long long* p0 = mypub + (size_t)((s - 1) & 1) * 512 + e0;
            unsigned int want = (unsigned)s;
            unsigned long long w0 = __hip_atomic_load(p0,     __ATOMIC_RELAXED, __HIP_MEMORY_SCOPE_AGENT);
            unsigned long long w1 = __hip_atomic_load(p0 + 1, __ATOMIC_RELAXED, __HIP_MEMORY_SCOPE_AGENT);
            while ((unsigned)(w0 >> 32) < want) {
                __builtin_amdgcn_s_sleep(1);
                w0 = __hip_atomic_load(p0, __ATOMIC_RELAXED, __HIP_MEMORY_SCOPE_AGENT);
            }
            while ((unsigned)(w1 >> 32) < want) {
                __builtin_amdgcn_s_sleep(1);
                w1 = __hip_atomic_load(p0 + 1, __ATOMIC_RELAXED, __HIP_MEMORY_SCOPE_AGENT);
            }
            float f0, f1;
            __builtin_memcpy(&f0, &w0, 4);
            __builtin_memcpy(&f1, &w1, 4);
            h_sh[par][pq][pj] = f0; h_sh[par][pq][pj + 1] = f1;
        }
        BAR_LGKM();                      // h_sh[par] ready (no vmcnt drain)

        // 128-wide partial dot (columns q*128 .. q*128+127)
        float a0 = 0.f, a1 = 0.f, a2 = 0.f, a3 = 0.f;
        const float4* hq = (const float4*)(&h_sh[par][q][0]);
#pragma unroll
        for (int j = 0; j < 32; ++j) {
            float4 hv = hq[j];
            a0 += w4[j].x * hv.x; a1 += w4[j].y * hv.y;
            a2 += w4[j].z * hv.z; a3 += w4[j].w * hv.w;
        }
        float dot = (a0 + a1) + (a2 + a3);
        dot += __shfl_xor(dot, 1);
        dot += __shfl_xor(dot, 2);       // all 4 q-lanes now hold gate dot
        int base = tid & ~15;
        float di = __shfl(dot, base + 0);
        float df = __shfl(dot, base + 4);
        float dg = __shfl(dot, base + 8);
        float dg_o = __shfl(dot, base + 12);
        if (leader) {
            float gi = di + pe0, gf = df + pe1, gg = dg + pe2, go = dg_o + pe3;
            float si = fast_sig(gi);
            float sf = fast_sig(gf);
            float so = fast_sig(go);
            float tg = fast_tanh(gg);
            c_state = sf * c_state + si * tg;
            float hval = so * fast_tanh(c_state);
            unsigned int hb; __builtin_memcpy(&hb, &hval, 4);
            unsigned long long wv = ((unsigned long long)(unsigned)(s + 1) << 32) | (unsigned long long)hb;
            __hip_atomic_store(mypub + (size_t)par * 512 + hu0 + u, wv,
                               __ATOMIC_RELAXED, __HIP_MEMORY_SCOPE_AGENT);
            H[(size_t)t * 1024 + dir * 512 + hu0 + u] = hval;
        }
        // no second barrier: next step writes h_sh[par^1] (distinct buffer);
        // common barrier bounds skew to <2 steps.
    }
}

// ---------------- Viterbi forward: single WG, one barrier/step, shfl reduce ----------------
__global__ __launch_bounds__(1024) void viterbi_fwd_kernel(
    const float* __restrict__ feats, const float* __restrict__ trans,
    float* __restrict__ fv_all)
{
    __shared__ float fv[2][256];
    int tid = threadIdx.x;
    int j = tid >> 2, q = tid & 3;      // tag j, quarter q
    float4 Tr[16];
#pragma unroll
    for (int b = 0; b < 16; ++b)
        Tr[b] = *(const float4*)(trans + (size_t)j * 256 + q * 64 + b * 4);
    if (tid < 256) fv[0][tid] = (tid == START_TAG) ? 0.f : NEGV;
    __syncthreads();
    for (int t = 0; t < T_LEN; ++t) {
        int p = t & 1;
        float ft = (q == 0) ? feats[(size_t)t * 256 + j] : 0.f;
        const float4* fq = (const float4*)(&fv[p][q * 64]);
        float m0 = -1e30f, m1 = -1e30f;
#pragma unroll
        for (int b = 0; b < 16; ++b) {
            float4 f4 = fq[b];
            float s0 = f4.x + Tr[b].x, s1 = f4.y + Tr[b].y;
            float s2 = f4.z + Tr[b].z, s3 = f4.w + Tr[b].w;
            m0 = fmaxf(fmaxf(m0, s0), s1);   // v_max3
            m1 = fmaxf(fmaxf(m1, s2), s3);
        }
        float m = fmaxf(m0, m1);
        m = fmaxf(m, __shfl_xor(m, 1));
        m = fmaxf(m, __shfl_xor(m, 2));
        if (q == 0) {
            float v = m + ft;
            fv[p ^ 1][j] = v;
            fv_all[(size_t)t * 256 + j] = v;
        }
        BAR_LGKM();
    }
}

// ---------------- 256x256 transpose of trans ----------------
__global__ __launch_bounds__(256) void transpose_kernel(
    const float* __restrict__ in, float* __restrict__ out)
{
    __shared__ float tile[16][17];
    int bx = blockIdx.x & 15, by = blockIdx.x >> 4;
    int tx = threadIdx.x & 15, ty = threadIdx.x >> 4;
    tile[ty][tx] = in[(size_t)(by * 16 + ty) * 256 + bx * 16 + tx];
    __syncthreads();
    out[(size_t)(bx * 16 + ty) * 256 + by * 16 + tx] = tile[tx][ty];
}

// ---------------- backpointers, recomputed fully parallel (coalesced) ----------------
__global__ __launch_bounds__(256) void bp_kernel(
    const float* __restrict__ fv_all, const float* __restrict__ transT,
    unsigned char* __restrict__ bp)
{
    __shared__ float fp[256];
    int t = blockIdx.x;
    int j = threadIdx.x;
    fp[j] = (t == 0) ? ((j == START_TAG) ? 0.f : NEGV)
                     : fv_all[(size_t)(t - 1) * 256 + j];
    __syncthreads();
    float m = -1e30f; int mi = 0;
#pragma unroll 4
    for (int i = 0; i < 256; ++i) {
        float s = fp[i] + transT[(size_t)i * 256 + j];   // lane-coalesced
        if (s > m) { m = s; mi = i; }   // strict > : first max index (jnp.argmax)
    }
    bp[(size_t)t * 256 + j] = (unsigned char)mi;
}

// ---------------- segmented backtrace: per-segment tag-map evolution ----------------
__global__ __launch_bounds__(256) void evol_kernel(
    const unsigned char* __restrict__ bp, unsigned char* __restrict__ evol)
{
    __shared__ unsigned char tm[256];
    __shared__ unsigned char row[256];
    int s = blockIdx.x;
    int tid = threadIdx.x;
    int t_top = s * 64 + 63;
    tm[tid] = (unsigned char)tid;
    evol[(size_t)t_top * 256 + tid] = (unsigned char)tid;
    __syncthreads();
    for (int t = t_top - 1; t >= s * 64; --t) {
        row[tid] = bp[(size_t)(t + 1) * 256 + tid];
        __syncthreads();
        unsigned char nt = row[tm[tid]];
        tm[tid] = nt;
        evol[(size_t)t * 256 + tid] = nt;
        __syncthreads();
    }
}

__global__ __launch_bounds__(256) void finalize_kernel(
    const float* __restrict__ fv_all, const float* __restrict__ trans,
    const unsigned char* __restrict__ bp, const unsigned char* __restrict__ evol,
    float* __restrict__ out)
{
    __shared__ float term[256];
    __shared__ unsigned char top[64];
    int tid = threadIdx.x;
    term[tid] = fv_all[(size_t)(T_LEN - 1) * 256 + tid] + trans[STOP_TAG * 256 + tid];
    __syncthreads();
    if (tid == 0) {
        float m = term[0]; int best = 0;
        for (int i = 1; i < 256; ++i) if (term[i] > m) { m = term[i]; best = i; }
        out[0] = m;
        int tag = best;
        top[63] = (unsigned char)tag;
        for (int s2 = 63; s2 >= 1; --s2) {
            int tb = s2 * 64;
            int pb = evol[(size_t)tb * 256 + tag];     // path[s2*64]
            tag = bp[(size_t)tb * 256 + pb];           // path[s2*64 - 1]
            top[s2 - 1] = (unsigned char)tag;
        }
    }
    __syncthreads();
    for (int t = tid; t < T_LEN; t += 256)
        out[1 + t] = (float)evol[(size_t)t * 256 + top[t >> 6]];
}

// ---------------- host launcher ----------------
extern "C" void kernel_launch(void* const* d_in, const int* in_sizes, int n_in,
                              void* d_out, int out_size, void* d_ws, size_t ws_size,
                              hipStream_t stream)
{
    const int*   src     = (const int*)d_in[0];
    const float* emb     = (const float*)d_in[2];
    const float* W_ih_f  = (const float*)d_in[3];
    const float* W_hh_f  = (const float*)d_in[4];
    const float* b_ih_f  = (const float*)d_in[5];
    const float* b_hh_f  = (const float*)d_in[6];
    const float* W_ih_b  = (const float*)d_in[7];
    const float* W_hh_b  = (const float*)d_in[8];
    const float* b_ih_b  = (const float*)d_in[9];
    const float* b_hh_b  = (const float*)d_in[10];
    const float* W_tag   = (const float*)d_in[11];
    const float* b_tag   = (const float*)d_in[12];
    const float* trans   = (const float*)d_in[13];
    float* out = (float*)d_out;

    char* w = (char*)d_ws;
    unsigned long long* pub = (unsigned long long*)w;   // 2 dir x 2 slot x 512 x 8B = 16 KB
    size_t off = 16384;
    float* PE_f = (float*)(w + off); off += (size_t)NVOC * G4 * 4;
    float* PE_b = (float*)(w + off); off += (size_t)NVOC * G4 * 4;
    float* H    = (float*)(w + off); off += (size_t)T_LEN * 1024 * 4;
    float* feats= (float*)(w + off); off += (size_t)T_LEN * 256 * 4;
    float* fv   = (float*)(w + off); off += (size_t)T_LEN * 256 * 4;
    float* transT = (float*)(w + off); off += (size_t)256 * 256 * 4;
    unsigned char* bp   = (unsigned char*)(w + off); off += (size_t)T_LEN * 256;
    unsigned char* evol = (unsigned char*)(w + off); off += (size_t)T_LEN * 256;

    hipMemsetAsync(pub, 0, 16384, stream);

    // PE = embedding @ W_ih^T + b_ih + b_hh   (256 x 2048)
    gemm_abt<<<dim3(NVOC / 64, G4 / 64), 256, 0, stream>>>(emb, W_ih_f, b_ih_f, b_hh_f, PE_f, NVOC, G4, EMBD);
    gemm_abt<<<dim3(NVOC / 64, G4 / 64), 256, 0, stream>>>(emb, W_ih_b, b_ih_b, b_hh_b, PE_b, NVOC, G4, EMBD);
    transpose_kernel<<<256, 256, 0, stream>>>(trans, transT);

    lstm_kernel<<<64, 256, 0, stream>>>(src, PE_f, PE_b, W_hh_f, W_hh_b, H, pub);

    // feats = H @ W_tag^T + b_tag   (4096 x 256)
    gemm_abt<<<dim3(T_LEN / 64, 256 / 64), 256, 0, stream>>>(H, W_tag, b_tag, nullptr, feats, T_LEN, 256, 1024);

    viterbi_fwd_kernel<<<1, 1024, 0, stream>>>(feats, trans, fv);
    bp_kernel<<<T_LEN, 256, 0, stream>>>(fv, transT, bp);
    evol_kernel<<<T_LEN / 64, 256, 0, stream>>>(bp, evol);
    finalize_kernel<<<1, 256, 0, stream>>>(fv, trans, bp, evol, out);
}

// Round 4
// 10523.199 us; speedup vs baseline: 1.4840x; 1.4840x over previous
//
#include <hip/hip_runtime.h>
#include <stdint.h>

#define T_LEN 4096
#define NVOC 256
#define EMBD 512
#define HID 512
#define G4 2048
#define NEGV (-10000.0f)
#define START_TAG 0
#define STOP_TAG 1
#define MAGIC1 0x1111111111111111ULL
#define MAGIC2 0x2222222222222222ULL

// raw workgroup barrier: wait LDS ops only (no vmcnt drain)
#define BAR_LGKM() do { \
    asm volatile("s_waitcnt lgkmcnt(0)\n\ts_barrier" ::: "memory"); \
    __builtin_amdgcn_sched_barrier(0); \
} while (0)

// ---------------- generic C[M,N] = A[M,K] @ B[N,K]^T + bias0 + bias1 ----------------
__global__ __launch_bounds__(256) void gemm_abt(
    const float* __restrict__ A, const float* __restrict__ B,
    const float* __restrict__ bias0, const float* __restrict__ bias1,
    float* __restrict__ C, int M, int N, int K)
{
    __shared__ float As[16][65];
    __shared__ float Bs[16][65];
    int m0 = blockIdx.x * 64, n0 = blockIdx.y * 64;
    int tid = threadIdx.x;
    int lr = tid >> 2;
    int lk = (tid & 3) << 2;
    int tr = tid & 15, tc = tid >> 4;
    float acc[4][4] = {};
    for (int k0 = 0; k0 < K; k0 += 16) {
        float4 av = *(const float4*)(A + (size_t)(m0 + lr) * K + k0 + lk);
        float4 bv = *(const float4*)(B + (size_t)(n0 + lr) * K + k0 + lk);
        As[lk + 0][lr] = av.x; As[lk + 1][lr] = av.y; As[lk + 2][lr] = av.z; As[lk + 3][lr] = av.w;
        Bs[lk + 0][lr] = bv.x; Bs[lk + 1][lr] = bv.y; Bs[lk + 2][lr] = bv.z; Bs[lk + 3][lr] = bv.w;
        __syncthreads();
#pragma unroll
        for (int kk = 0; kk < 16; ++kk) {
            float a[4], b[4];
#pragma unroll
            for (int x = 0; x < 4; ++x) a[x] = As[kk][tr * 4 + x];
#pragma unroll
            for (int y = 0; y < 4; ++y) b[y] = Bs[kk][tc * 4 + y];
#pragma unroll
            for (int y = 0; y < 4; ++y)
#pragma unroll
                for (int x = 0; x < 4; ++x)
                    acc[y][x] += a[x] * b[y];
        }
        __syncthreads();
    }
#pragma unroll
    for (int y = 0; y < 4; ++y) {
        int n = n0 + tc * 4 + y;
        float bb = bias0 ? bias0[n] : 0.f;
        if (bias1) bb += bias1[n];
#pragma unroll
        for (int x = 0; x < 4; ++x)
            C[(size_t)(m0 + tr * 4 + x) * N + n] = acc[y][x] + bb;
    }
}

__device__ __forceinline__ float fast_sig(float x) {
    return __builtin_amdgcn_rcpf(1.f + __expf(-x));
}
__device__ __forceinline__ float fast_tanh(float x) {
    return 2.f * __builtin_amdgcn_rcpf(1.f + __expf(-2.f * x)) - 1.f;
}

// sc0-only load: bypass L1, served by (same-XCD) L2 — NOT MALL-routed.
__device__ __forceinline__ unsigned long long load_sc0_u64(const unsigned long long* p) {
    unsigned long long v;
    asm volatile("global_load_dwordx2 %0, %1, off sc0\n\ts_waitcnt vmcnt(0)"
                 : "=v"(v) : "v"(p) : "memory");
    return v;
}

__device__ __forceinline__ unsigned long long pub_load(const unsigned long long* p, bool fast) {
    if (fast) return load_sc0_u64(p);
    return __hip_atomic_load(p, __ATOMIC_RELAXED, __HIP_MEMORY_SCOPE_AGENT);
}
__device__ __forceinline__ void pub_store(unsigned long long* p, unsigned long long v, bool fast) {
    if (fast) *(volatile unsigned long long*)p = v;
    else __hip_atomic_store(p, v, __ATOMIC_RELAXED, __HIP_MEMORY_SCOPE_AGENT);
}

// device-wide mini-barrier over the 64 real WGs (agent scope, one-time use)
__device__ __forceinline__ void gbar(unsigned int* ctr) {
    __syncthreads();
    if (threadIdx.x == 0) {
        __hip_atomic_fetch_add(ctr, 1u, __ATOMIC_RELAXED, __HIP_MEMORY_SCOPE_AGENT);
        while (__hip_atomic_load(ctr, __ATOMIC_RELAXED, __HIP_MEMORY_SCOPE_AGENT) < 64u)
            __builtin_amdgcn_s_sleep(2);
    }
    __syncthreads();
}

// ---------------- persistent BiLSTM ----------------
// grid 256: blocks with (b&7)==0 -> fwd WGs (hopefully one XCD), ==1 -> bwd; others exit.
// Runtime coherence test picks per-direction exchange mode:
//   fast: plain store + sc0 load (same-XCD L2)   |   safe: agent atomics (MALL)
__global__ __launch_bounds__(256) void lstm_kernel(
    const int* __restrict__ src,
    const float* __restrict__ PE_f, const float* __restrict__ PE_b,
    const float* __restrict__ Whh_f, const float* __restrict__ Whh_b,
    float* __restrict__ H, unsigned long long* __restrict__ pub)
{
    int b = blockIdx.x;
    if ((b & 7) > 1) return;             // empty filler block
    int dir = b & 7;                     // 0 = fwd, 1 = bwd
    int wg  = b >> 3;                    // 0..31
    const float* PE  = dir ? PE_b : PE_f;
    const float* Whh = dir ? Whh_b : Whh_f;
    unsigned long long* mypub = pub + (size_t)dir * 1024;   // [slot][512]
    unsigned long long* coh = pub + 2048;                   // 64 test slots
    unsigned int* ctr = (unsigned int*)(pub + 2048 + 64);   // c0..c3, bad0, bad1

    int tid = threadIdx.x;
    int u = tid >> 4;                   // unit 0..15
    int g = (tid >> 2) & 3;             // gate 0..3
    int q = tid & 3;                    // column quarter
    int hu0 = wg * 16;
    int grow = g * 512 + hu0 + u;
    int wid = dir * 32 + wg;

    // ---- coherence self-test (decides exchange mode, per direction) ----
    if (tid == 0) *(volatile unsigned long long*)&coh[wid] = MAGIC1;
    gbar(ctr + 0);
    if (tid == 0) {                      // prime sc0/L2 path with current lines
        unsigned long long acc = 0;
        for (int k = 0; k < 32; ++k) {
            acc ^= load_sc0_u64(&coh[dir * 32 + k]);
            acc ^= load_sc0_u64(&coh[dir * 32 + k]);
        }
        asm volatile("" :: "v"(acc));    // keep live (rule #17)
    }
    gbar(ctr + 1);
    if (tid == 0) *(volatile unsigned long long*)&coh[wid] = MAGIC2;
    gbar(ctr + 2);
    if (tid == 0) {
        bool ok = true;
        for (int k = 0; k < 32; ++k)
            ok &= (load_sc0_u64(&coh[dir * 32 + k]) == MAGIC2);
        if (!ok)
            __hip_atomic_fetch_add(&ctr[4 + dir], 1u, __ATOMIC_RELAXED, __HIP_MEMORY_SCOPE_AGENT);
    }
    gbar(ctr + 3);
    __shared__ int mode_sh;
    if (tid == 0)
        mode_sh = (__hip_atomic_load(&ctr[4 + dir], __ATOMIC_RELAXED, __HIP_MEMORY_SCOPE_AGENT) == 0u);
    __syncthreads();
    const bool fast = (mode_sh != 0);

    // ---- weights -> registers (32 float4 = 128 VGPR) ----
    float4 w4[32];
    const float4* wsrc = (const float4*)(Whh + (size_t)grow * 512 + q * 128);
#pragma unroll
    for (int j = 0; j < 32; ++j) w4[j] = wsrc[j];

    __shared__ __align__(16) float h_sh[2][4][132];
    float c_state = 0.f;
    bool leader = ((tid & 15) == 0);

    int e0 = tid * 2;
    int pq = e0 >> 7, pj = e0 & 127;

    for (int s = 0; s < T_LEN; ++s) {
        int par = s & 1;
        int t = dir ? (T_LEN - 1 - s) : s;
        int st = src[t];
        float pe0 = 0.f, pe1 = 0.f, pe2 = 0.f, pe3 = 0.f;
        if (leader) {
            const float* pb = PE + (size_t)st * G4 + hu0 + u;
            pe0 = pb[0]; pe1 = pb[512]; pe2 = pb[1024]; pe3 = pb[1536];
        }
        if (s == 0) {
            h_sh[0][pq][pj] = 0.f; h_sh[0][pq][pj + 1] = 0.f;
        } else {
            unsigned long long* p0 = mypub + (size_t)((s - 1) & 1) * 512 + e0;
            unsigned int want = (unsigned)s;
            unsigned long long w0 = pub_load(p0, fast);
            unsigned long long w1 = pub_load(p0 + 1, fast);
            while ((unsigned)(w0 >> 32) < want) {
                __builtin_amdgcn_s_sleep(1);
                w0 = pub_load(p0, fast);
            }
            while ((unsigned)(w1 >> 32) < want) {
                __builtin_amdgcn_s_sleep(1);
                w1 = pub_load(p0 + 1, fast);
            }
            float f0, f1;
            __builtin_memcpy(&f0, &w0, 4);
            __builtin_memcpy(&f1, &w1, 4);
            h_sh[par][pq][pj] = f0; h_sh[par][pq][pj + 1] = f1;
        }
        BAR_LGKM();                      // h_sh[par] ready

        float a0 = 0.f, a1 = 0.f, a2 = 0.f, a3 = 0.f;
        const float4* hq = (const float4*)(&h_sh[par][q][0]);
#pragma unroll
        for (int j = 0; j < 32; ++j) {
            float4 hv = hq[j];
            a0 += w4[j].x * hv.x; a1 += w4[j].y * hv.y;
            a2 += w4[j].z * hv.z; a3 += w4[j].w * hv.w;
        }
        float dot = (a0 + a1) + (a2 + a3);
        dot += __shfl_xor(dot, 1);
        dot += __shfl_xor(dot, 2);
        int base = tid & ~15;
        float di = __shfl(dot, base + 0);
        float df = __shfl(dot, base + 4);
        float dg = __shfl(dot, base + 8);
        float dgo = __shfl(dot, base + 12);
        if (leader) {
            float gi = di + pe0, gf = df + pe1, gg = dg + pe2, go = dgo + pe3;
            float si = fast_sig(gi);
            float sf = fast_sig(gf);
            float so = fast_sig(go);
            float tg = fast_tanh(gg);
            c_state = sf * c_state + si * tg;
            float hval = so * fast_tanh(c_state);
            unsigned int hb; __builtin_memcpy(&hb, &hval, 4);
            unsigned long long wv = ((unsigned long long)(unsigned)(s + 1) << 32) | (unsigned long long)hb;
            pub_store(mypub + (size_t)par * 512 + hu0 + u, wv, fast);
            H[(size_t)t * 1024 + dir * 512 + hu0 + u] = hval;
        }
        // next step writes h_sh[par^1]; all-to-all tag coupling bounds skew <2 steps
    }
}

// ---------------- Viterbi forward: 512 thr, broadcast LDS reads, 1 barrier/step ----------------
__global__ __launch_bounds__(512) void viterbi_fwd_kernel(
    const float* __restrict__ feats, const float* __restrict__ trans,
    float* __restrict__ fv_all)
{
    __shared__ __align__(16) float fvb[2][256];
    int tid = threadIdx.x;
    int wv = tid >> 6;           // wave 0..7
    int l  = tid & 63;
    int h  = l >> 5;             // i-half 0/1
    int jj = l & 31;
    int j  = wv * 32 + jj;       // output tag
    float4 Tr[32];
    const float4* tr = (const float4*)(trans + (size_t)j * 256 + h * 128);
#pragma unroll
    for (int k = 0; k < 32; ++k) Tr[k] = tr[k];
    if (tid < 256) fvb[0][tid] = (tid == START_TAG) ? 0.f : NEGV;
    bool h0 = (h == 0);
    float ft_next = h0 ? feats[j] : 0.f;
    __syncthreads();
    for (int t = 0; t < T_LEN; ++t) {
        int p = t & 1;
        float ft = ft_next;
        if (h0 && t + 1 < T_LEN) ft_next = feats[(size_t)(t + 1) * 256 + j];
        const float4* fq = (const float4*)(&fvb[p][h * 128]);   // wave-broadcast reads
        float m0 = -1e30f, m1 = -1e30f;
#pragma unroll
        for (int k = 0; k < 32; ++k) {
            float4 f4 = fq[k];
            float s0 = f4.x + Tr[k].x, s1 = f4.y + Tr[k].y;
            float s2 = f4.z + Tr[k].z, s3 = f4.w + Tr[k].w;
            m0 = fmaxf(fmaxf(m0, s0), s1);   // v_max3
            m1 = fmaxf(fmaxf(m1, s2), s3);
        }
        float m = fmaxf(m0, m1);
        m = fmaxf(m, __shfl_xor(m, 32));     // combine i-halves
        if (h0) {
            float v = m + ft;
            fvb[p ^ 1][j] = v;
            fv_all[(size_t)t * 256 + j] = v;
        }
        BAR_LGKM();
    }
}

// ---------------- 256x256 transpose of trans ----------------
__global__ __launch_bounds__(256) void transpose_kernel(
    const float* __restrict__ in, float* __restrict__ out)
{
    __shared__ float tile[16][17];
    int bx = blockIdx.x & 15, by = blockIdx.x >> 4;
    int tx = threadIdx.x & 15, ty = threadIdx.x >> 4;
    tile[ty][tx] = in[(size_t)(by * 16 + ty) * 256 + bx * 16 + tx];
    __syncthreads();
    out[(size_t)(bx * 16 + ty) * 256 + by * 16 + tx] = tile[tx][ty];
}

// ---------------- backpointers, fully parallel (coalesced via transT) ----------------
__global__ __launch_bounds__(256) void bp_kernel(
    const float* __restrict__ fv_all, const float* __restrict__ transT,
    unsigned char* __restrict__ bp)
{
    __shared__ float fp[256];
    int t = blockIdx.x;
    int j = threadIdx.x;
    fp[j] = (t == 0) ? ((j == START_TAG) ? 0.f : NEGV)
                     : fv_all[(size_t)(t - 1) * 256 + j];
    __syncthreads();
    float m = -1e30f; int mi = 0;
#pragma unroll 4
    for (int i = 0; i < 256; ++i) {
        float s = fp[i] + transT[(size_t)i * 256 + j];
        if (s > m) { m = s; mi = i; }   // strict > : first max index (jnp.argmax)
    }
    bp[(size_t)t * 256 + j] = (unsigned char)mi;
}

// ---------------- segmented backtrace ----------------
__global__ __launch_bounds__(256) void evol_kernel(
    const unsigned char* __restrict__ bp, unsigned char* __restrict__ evol)
{
    __shared__ unsigned char tm[256];
    __shared__ unsigned char row[256];
    int s = blockIdx.x;
    int tid = threadIdx.x;
    int t_top = s * 64 + 63;
    tm[tid] = (unsigned char)tid;
    evol[(size_t)t_top * 256 + tid] = (unsigned char)tid;
    __syncthreads();
    for (int t = t_top - 1; t >= s * 64; --t) {
        row[tid] = bp[(size_t)(t + 1) * 256 + tid];
        __syncthreads();
        unsigned char nt = row[tm[tid]];
        tm[tid] = nt;
        evol[(size_t)t * 256 + tid] = nt;
        __syncthreads();
    }
}

__global__ __launch_bounds__(256) void finalize_kernel(
    const float* __restrict__ fv_all, const float* __restrict__ trans,
    const unsigned char* __restrict__ bp, const unsigned char* __restrict__ evol,
    float* __restrict__ out)
{
    __shared__ float term[256];
    __shared__ unsigned char top[64];
    int tid = threadIdx.x;
    term[tid] = fv_all[(size_t)(T_LEN - 1) * 256 + tid] + trans[STOP_TAG * 256 + tid];
    __syncthreads();
    if (tid == 0) {
        float m = term[0]; int best = 0;
        for (int i = 1; i < 256; ++i) if (term[i] > m) { m = term[i]; best = i; }
        out[0] = m;
        int tag = best;
        top[63] = (unsigned char)tag;
        for (int s2 = 63; s2 >= 1; --s2) {
            int tb = s2 * 64;
            int pb = evol[(size_t)tb * 256 + tag];
            tag = bp[(size_t)tb * 256 + pb];
            top[s2 - 1] = (unsigned char)tag;
        }
    }
    __syncthreads();
    for (int t = tid; t < T_LEN; t += 256)
        out[1 + t] = (float)evol[(size_t)t * 256 + top[t >> 6]];
}

// ---------------- host launcher ----------------
extern "C" void kernel_launch(void* const* d_in, const int* in_sizes, int n_in,
                              void* d_out, int out_size, void* d_ws, size_t ws_size,
                              hipStream_t stream)
{
    const int*   src     = (const int*)d_in[0];
    const float* emb     = (const float*)d_in[2];
    const float* W_ih_f  = (const float*)d_in[3];
    const float* W_hh_f  = (const float*)d_in[4];
    const float* b_ih_f  = (const float*)d_in[5];
    const float* b_hh_f  = (const float*)d_in[6];
    const float* W_ih_b  = (const float*)d_in[7];
    const float* W_hh_b  = (const float*)d_in[8];
    const float* b_ih_b  = (const float*)d_in[9];
    const float* b_hh_b  = (const float*)d_in[10];
    const float* W_tag   = (const float*)d_in[11];
    const float* b_tag   = (const float*)d_in[12];
    const float* trans   = (const float*)d_in[13];
    float* out = (float*)d_out;

    char* w = (char*)d_ws;
    unsigned long long* pub = (unsigned long long*)w;   // 16KB pub + 512B coh + ctrs
    size_t off = 32768;
    float* PE_f = (float*)(w + off); off += (size_t)NVOC * G4 * 4;
    float* PE_b = (float*)(w + off); off += (size_t)NVOC * G4 * 4;
    float* H    = (float*)(w + off); off += (size_t)T_LEN * 1024 * 4;
    float* feats= (float*)(w + off); off += (size_t)T_LEN * 256 * 4;
    float* fv   = (float*)(w + off); off += (size_t)T_LEN * 256 * 4;
    float* transT = (float*)(w + off); off += (size_t)256 * 256 * 4;
    unsigned char* bp   = (unsigned char*)(w + off); off += (size_t)T_LEN * 256;
    unsigned char* evol = (unsigned char*)(w + off); off += (size_t)T_LEN * 256;

    hipMemsetAsync(pub, 0, 17408, stream);   // pub + coh slots + counters

    gemm_abt<<<dim3(NVOC / 64, G4 / 64), 256, 0, stream>>>(emb, W_ih_f, b_ih_f, b_hh_f, PE_f, NVOC, G4, EMBD);
    gemm_abt<<<dim3(NVOC / 64, G4 / 64), 256, 0, stream>>>(emb, W_ih_b, b_ih_b, b_hh_b, PE_b, NVOC, G4, EMBD);
    transpose_kernel<<<256, 256, 0, stream>>>(trans, transT);

    lstm_kernel<<<256, 256, 0, stream>>>(src, PE_f, PE_b, W_hh_f, W_hh_b, H, pub);

    gemm_abt<<<dim3(T_LEN / 64, 256 / 64), 256, 0, stream>>>(H, W_tag, b_tag, nullptr, feats, T_LEN, 256, 1024);

    viterbi_fwd_kernel<<<1, 512, 0, stream>>>(feats, trans, fv);
    bp_kernel<<<T_LEN, 256, 0, stream>>>(fv, transT, bp);
    evol_kernel<<<T_LEN / 64, 256, 0, stream>>>(bp, evol);
    finalize_kernel<<<1, 256, 0, stream>>>(fv, trans, bp, evol, out);
}

// Round 5
// 10021.367 us; speedup vs baseline: 1.5583x; 1.0501x over previous
//
#include <hip/hip_runtime.h>
#include <stdint.h>

#define T_LEN 4096
#define NVOC 256
#define EMBD 512
#define HID 512
#define G4 2048
#define NEGV (-10000.0f)
#define START_TAG 0
#define STOP_TAG 1

// raw workgroup barrier: wait LDS ops only (no vmcnt drain)
#define BAR_LGKM() do { \
    asm volatile("s_waitcnt lgkmcnt(0)\n\ts_barrier" ::: "memory"); \
    __builtin_amdgcn_sched_barrier(0); \
} while (0)

// ---------------- generic C[M,N] = A[M,K] @ B[N,K]^T + bias0 + bias1 ----------------
__global__ __launch_bounds__(256) void gemm_abt(
    const float* __restrict__ A, const float* __restrict__ B,
    const float* __restrict__ bias0, const float* __restrict__ bias1,
    float* __restrict__ C, int M, int N, int K)
{
    __shared__ float As[16][65];
    __shared__ float Bs[16][65];
    int m0 = blockIdx.x * 64, n0 = blockIdx.y * 64;
    int tid = threadIdx.x;
    int lr = tid >> 2;
    int lk = (tid & 3) << 2;
    int tr = tid & 15, tc = tid >> 4;
    float acc[4][4] = {};
    for (int k0 = 0; k0 < K; k0 += 16) {
        float4 av = *(const float4*)(A + (size_t)(m0 + lr) * K + k0 + lk);
        float4 bv = *(const float4*)(B + (size_t)(n0 + lr) * K + k0 + lk);
        As[lk + 0][lr] = av.x; As[lk + 1][lr] = av.y; As[lk + 2][lr] = av.z; As[lk + 3][lr] = av.w;
        Bs[lk + 0][lr] = bv.x; Bs[lk + 1][lr] = bv.y; Bs[lk + 2][lr] = bv.z; Bs[lk + 3][lr] = bv.w;
        __syncthreads();
#pragma unroll
        for (int kk = 0; kk < 16; ++kk) {
            float a[4], b[4];
#pragma unroll
            for (int x = 0; x < 4; ++x) a[x] = As[kk][tr * 4 + x];
#pragma unroll
            for (int y = 0; y < 4; ++y) b[y] = Bs[kk][tc * 4 + y];
#pragma unroll
            for (int y = 0; y < 4; ++y)
#pragma unroll
                for (int x = 0; x < 4; ++x)
                    acc[y][x] += a[x] * b[y];
        }
        __syncthreads();
    }
#pragma unroll
    for (int y = 0; y < 4; ++y) {
        int n = n0 + tc * 4 + y;
        float bb = bias0 ? bias0[n] : 0.f;
        if (bias1) bb += bias1[n];
#pragma unroll
        for (int x = 0; x < 4; ++x)
            C[(size_t)(m0 + tr * 4 + x) * N + n] = acc[y][x] + bb;
    }
}

__device__ __forceinline__ float fast_sig(float x) {
    return __builtin_amdgcn_rcpf(1.f + __expf(-x));
}
__device__ __forceinline__ float fast_tanh(float x) {
    return 2.f * __builtin_amdgcn_rcpf(1.f + __expf(-2.f * x)) - 1.f;
}

// ---------------- persistent BiLSTM ----------------
// 64 blocks x 512 threads. blocks 0..31: forward, 32..63: backward.
// thread map: q = tid&7 (64-col eighth), g = (tid>>3)&3 (gate), u = tid>>5 (unit).
// Weights: 16 float4 = 64 VGPR per thread, forced resident via launch_bounds(512,1).
// h exchange: tagged u64 words, relaxed agent atomics (fence-free), 2-slot rotation.
__global__ __launch_bounds__(512, 1) void lstm_kernel(
    const int* __restrict__ src,
    const float* __restrict__ PE_f, const float* __restrict__ PE_b,
    const float* __restrict__ Whh_f, const float* __restrict__ Whh_b,
    float* __restrict__ H, unsigned long long* __restrict__ pub)
{
    int wg  = blockIdx.x & 31;
    int dir = blockIdx.x >> 5;          // 0 = fwd, 1 = bwd
    const float* PE  = dir ? PE_b : PE_f;
    const float* Whh = dir ? Whh_b : Whh_f;
    unsigned long long* mypub = pub + (size_t)dir * 1024;   // [slot][512]

    int tid = threadIdx.x;
    int q = tid & 7;                    // column eighth (64 cols)
    int g = (tid >> 3) & 3;             // gate 0..3 (i,f,g,o)
    int u = tid >> 5;                   // unit 0..15
    int hu0 = wg * 16;
    int grow = g * 512 + hu0 + u;       // gate row in W_hh

    // weights -> registers (16 float4 = 64 VGPR)
    float4 w4[16];
    const float4* wsrc = (const float4*)(Whh + (size_t)grow * 512 + q * 64);
#pragma unroll
    for (int j = 0; j < 16; ++j) w4[j] = wsrc[j];

    // double-buffered; row stride 68 floats -> the 8 q-streams hit disjoint banks
    __shared__ __align__(16) float h_sh[2][8][68];
    float c_state = 0.f;                // valid in leader lanes
    bool leader = ((tid & 31) == 0);
    bool q0 = (q == 0);

    for (int s = 0; s < T_LEN; ++s) {
        int par = s & 1;
        int t = dir ? (T_LEN - 1 - s) : s;
        int st = src[t];
        float pe = 0.f;
        if (q0)                          // prefetch this gate's input projection
            pe = PE[(size_t)st * G4 + g * 512 + hu0 + u];

        if (s == 0) {
            h_sh[0][tid >> 6][tid & 63] = 0.f;
        } else {
            unsigned long long* p0 = mypub + (size_t)((s - 1) & 1) * 512 + tid;
            unsigned int want = (unsigned)s;
            unsigned long long w0 = __hip_atomic_load(p0, __ATOMIC_RELAXED, __HIP_MEMORY_SCOPE_AGENT);
            while ((unsigned)(w0 >> 32) < want) {
                __builtin_amdgcn_s_sleep(1);
                w0 = __hip_atomic_load(p0, __ATOMIC_RELAXED, __HIP_MEMORY_SCOPE_AGENT);
            }
            float f0; __builtin_memcpy(&f0, &w0, 4);
            h_sh[par][tid >> 6][tid & 63] = f0;
        }
        BAR_LGKM();                      // h_sh[par] ready (no vmcnt drain)

        // 64-wide partial dot (columns q*64 .. q*64+63)
        float a0 = 0.f, a1 = 0.f, a2 = 0.f, a3 = 0.f;
        const float4* hq = (const float4*)(&h_sh[par][q][0]);
#pragma unroll
        for (int j = 0; j < 16; ++j) {
            float4 hv = hq[j];
            a0 += w4[j].x * hv.x; a1 += w4[j].y * hv.y;
            a2 += w4[j].z * hv.z; a3 += w4[j].w * hv.w;
        }
        float dot = (a0 + a1) + (a2 + a3);
        dot += __shfl_xor(dot, 1);
        dot += __shfl_xor(dot, 2);
        dot += __shfl_xor(dot, 4);       // q==0 lanes hold full gate dot
        float val = dot + pe;            // gate pre-activation (q==0 lanes)
        int base = tid & ~31;
        float vf = __shfl(val, base + 8);
        float vg = __shfl(val, base + 16);
        float vo = __shfl(val, base + 24);
        if (leader) {                    // leader lane has gate i (g==0)
            float si = fast_sig(val);
            float sf = fast_sig(vf);
            float tg = fast_tanh(vg);
            float so = fast_sig(vo);
            c_state = sf * c_state + si * tg;
            float hval = so * fast_tanh(c_state);
            unsigned int hb; __builtin_memcpy(&hb, &hval, 4);
            unsigned long long wv = ((unsigned long long)(unsigned)(s + 1) << 32) | (unsigned long long)hb;
            __hip_atomic_store(mypub + (size_t)par * 512 + hu0 + u, wv,
                               __ATOMIC_RELAXED, __HIP_MEMORY_SCOPE_AGENT);
            H[(size_t)t * 1024 + dir * 512 + hu0 + u] = hval;
        }
        // next step writes h_sh[par^1]; 2-slot rotation + all-to-all tag coupling
        // bounds skew (overwrite of slot X gated on all WGs having consumed X).
    }
}

// ---------------- Viterbi forward: 512 thr, broadcast LDS reads, 1 barrier/step ----------------
__global__ __launch_bounds__(512, 1) void viterbi_fwd_kernel(
    const float* __restrict__ feats, const float* __restrict__ trans,
    float* __restrict__ fv_all)
{
    __shared__ __align__(16) float fvb[2][256];
    int tid = threadIdx.x;
    int wv = tid >> 6;           // wave 0..7
    int l  = tid & 63;
    int h  = l >> 5;             // i-half 0/1
    int jj = l & 31;
    int j  = wv * 32 + jj;       // output tag
    float4 Tr[32];               // 128 VGPR, resident via launch_bounds(512,1)
    const float4* tr = (const float4*)(trans + (size_t)j * 256 + h * 128);
#pragma unroll
    for (int k = 0; k < 32; ++k) Tr[k] = tr[k];
    if (tid < 256) fvb[0][tid] = (tid == START_TAG) ? 0.f : NEGV;
    bool h0 = (h == 0);
    float ft_next = h0 ? feats[j] : 0.f;
    __syncthreads();
    for (int t = 0; t < T_LEN; ++t) {
        int p = t & 1;
        float ft = ft_next;
        if (h0 && t + 1 < T_LEN) ft_next = feats[(size_t)(t + 1) * 256 + j];
        const float4* fq = (const float4*)(&fvb[p][h * 128]);   // wave-broadcast reads
        float m0 = -1e30f, m1 = -1e30f;
#pragma unroll
        for (int k = 0; k < 32; ++k) {
            float4 f4 = fq[k];
            float s0 = f4.x + Tr[k].x, s1 = f4.y + Tr[k].y;
            float s2 = f4.z + Tr[k].z, s3 = f4.w + Tr[k].w;
            m0 = fmaxf(fmaxf(m0, s0), s1);   // v_max3
            m1 = fmaxf(fmaxf(m1, s2), s3);
        }
        float m = fmaxf(m0, m1);
        m = fmaxf(m, __shfl_xor(m, 32));     // combine i-halves
        if (h0) {
            float v = m + ft;
            fvb[p ^ 1][j] = v;
            fv_all[(size_t)t * 256 + j] = v;
        }
        BAR_LGKM();
    }
}

// ---------------- 256x256 transpose of trans ----------------
__global__ __launch_bounds__(256) void transpose_kernel(
    const float* __restrict__ in, float* __restrict__ out)
{
    __shared__ float tile[16][17];
    int bx = blockIdx.x & 15, by = blockIdx.x >> 4;
    int tx = threadIdx.x & 15, ty = threadIdx.x >> 4;
    tile[ty][tx] = in[(size_t)(by * 16 + ty) * 256 + bx * 16 + tx];
    __syncthreads();
    out[(size_t)(bx * 16 + ty) * 256 + by * 16 + tx] = tile[tx][ty];
}

// ---------------- backpointers, fully parallel (coalesced via transT) ----------------
__global__ __launch_bounds__(256) void bp_kernel(
    const float* __restrict__ fv_all, const float* __restrict__ transT,
    unsigned char* __restrict__ bp)
{
    __shared__ float fp[256];
    int t = blockIdx.x;
    int j = threadIdx.x;
    fp[j] = (t == 0) ? ((j == START_TAG) ? 0.f : NEGV)
                     : fv_all[(size_t)(t - 1) * 256 + j];
    __syncthreads();
    float m = -1e30f; int mi = 0;
#pragma unroll 4
    for (int i = 0; i < 256; ++i) {
        float s = fp[i] + transT[(size_t)i * 256 + j];
        if (s > m) { m = s; mi = i; }   // strict > : first max index (jnp.argmax)
    }
    bp[(size_t)t * 256 + j] = (unsigned char)mi;
}

// ---------------- segmented backtrace ----------------
__global__ __launch_bounds__(256) void evol_kernel(
    const unsigned char* __restrict__ bp, unsigned char* __restrict__ evol)
{
    __shared__ unsigned char tm[256];
    __shared__ unsigned char row[256];
    int s = blockIdx.x;
    int tid = threadIdx.x;
    int t_top = s * 64 + 63;
    tm[tid] = (unsigned char)tid;
    evol[(size_t)t_top * 256 + tid] = (unsigned char)tid;
    __syncthreads();
    for (int t = t_top - 1; t >= s * 64; --t) {
        row[tid] = bp[(size_t)(t + 1) * 256 + tid];
        __syncthreads();
        unsigned char nt = row[tm[tid]];
        tm[tid] = nt;
        evol[(size_t)t * 256 + tid] = nt;
        __syncthreads();
    }
}

__global__ __launch_bounds__(256) void finalize_kernel(
    const float* __restrict__ fv_all, const float* __restrict__ trans,
    const unsigned char* __restrict__ bp, const unsigned char* __restrict__ evol,
    float* __restrict__ out)
{
    __shared__ float term[256];
    __shared__ unsigned char top[64];
    int tid = threadIdx.x;
    term[tid] = fv_all[(size_t)(T_LEN - 1) * 256 + tid] + trans[STOP_TAG * 256 + tid];
    __syncthreads();
    if (tid == 0) {
        float m = term[0]; int best = 0;
        for (int i = 1; i < 256; ++i) if (term[i] > m) { m = term[i]; best = i; }
        out[0] = m;
        int tag = best;
        top[63] = (unsigned char)tag;
        for (int s2 = 63; s2 >= 1; --s2) {
            int tb = s2 * 64;
            int pb = evol[(size_t)tb * 256 + tag];
            tag = bp[(size_t)tb * 256 + pb];
            top[s2 - 1] = (unsigned char)tag;
        }
    }
    __syncthreads();
    for (int t = tid; t < T_LEN; t += 256)
        out[1 + t] = (float)evol[(size_t)t * 256 + top[t >> 6]];
}

// ---------------- host launcher ----------------
extern "C" void kernel_launch(void* const* d_in, const int* in_sizes, int n_in,
                              void* d_out, int out_size, void* d_ws, size_t ws_size,
                              hipStream_t stream)
{
    const int*   src     = (const int*)d_in[0];
    const float* emb     = (const float*)d_in[2];
    const float* W_ih_f  = (const float*)d_in[3];
    const float* W_hh_f  = (const float*)d_in[4];
    const float* b_ih_f  = (const float*)d_in[5];
    const float* b_hh_f  = (const float*)d_in[6];
    const float* W_ih_b  = (const float*)d_in[7];
    const float* W_hh_b  = (const float*)d_in[8];
    const float* b_ih_b  = (const float*)d_in[9];
    const float* b_hh_b  = (const float*)d_in[10];
    const float* W_tag   = (const float*)d_in[11];
    const float* b_tag   = (const float*)d_in[12];
    const float* trans   = (const float*)d_in[13];
    float* out = (float*)d_out;

    char* w = (char*)d_ws;
    unsigned long long* pub = (unsigned long long*)w;   // 2 dir x 2 slot x 512 x 8B = 16 KB
    size_t off = 32768;
    float* PE_f = (float*)(w + off); off += (size_t)NVOC * G4 * 4;
    float* PE_b = (float*)(w + off); off += (size_t)NVOC * G4 * 4;
    float* H    = (float*)(w + off); off += (size_t)T_LEN * 1024 * 4;
    float* feats= (float*)(w + off); off += (size_t)T_LEN * 256 * 4;
    float* fv   = (float*)(w + off); off += (size_t)T_LEN * 256 * 4;
    float* transT = (float*)(w + off); off += (size_t)256 * 256 * 4;
    unsigned char* bp   = (unsigned char*)(w + off); off += (size_t)T_LEN * 256;
    unsigned char* evol = (unsigned char*)(w + off); off += (size_t)T_LEN * 256;

    hipMemsetAsync(pub, 0, 16384, stream);

    gemm_abt<<<dim3(NVOC / 64, G4 / 64), 256, 0, stream>>>(emb, W_ih_f, b_ih_f, b_hh_f, PE_f, NVOC, G4, EMBD);
    gemm_abt<<<dim3(NVOC / 64, G4 / 64), 256, 0, stream>>>(emb, W_ih_b, b_ih_b, b_hh_b, PE_b, NVOC, G4, EMBD);
    transpose_kernel<<<256, 256, 0, stream>>>(trans, transT);

    lstm_kernel<<<64, 512, 0, stream>>>(src, PE_f, PE_b, W_hh_f, W_hh_b, H, pub);

    gemm_abt<<<dim3(T_LEN / 64, 256 / 64), 256, 0, stream>>>(H, W_tag, b_tag, nullptr, feats, T_LEN, 256, 1024);

    viterbi_fwd_kernel<<<1, 512, 0, stream>>>(feats, trans, fv);
    bp_kernel<<<T_LEN, 256, 0, stream>>>(fv, transT, bp);
    evol_kernel<<<T_LEN / 64, 256, 0, stream>>>(bp, evol);
    finalize_kernel<<<1, 256, 0, stream>>>(fv, trans, bp, evol, out);
}